// Round 3
// baseline (328.651 us; speedup 1.0000x reference)
//
#include <hip/hip_runtime.h>

#define CAP 64

typedef short bf16x8 __attribute__((ext_vector_type(8)));
typedef float f32x4 __attribute__((ext_vector_type(4)));
typedef unsigned short u16;
typedef unsigned int u32;

__device__ __forceinline__ u16 f32_to_bf16(float f) {
  u32 b = __float_as_uint(f);
  b += 0x7fffu + ((b >> 16) & 1u);  // round to nearest even
  return (u16)(b >> 16);
}

// ---------------------------------------------------------------------------
// K0: X fp32 -> bf16, packed into d_out (dead until mlp overwrites it).
// ---------------------------------------------------------------------------
__global__ void convert_x_kernel(const float* __restrict__ X,
                                 u16* __restrict__ Xb, int n8) {
  int i = blockIdx.x * blockDim.x + threadIdx.x;
  if (i >= n8) return;
  float4 a = ((const float4*)X)[2 * i];
  float4 b = ((const float4*)X)[2 * i + 1];
  int4 o;
  o.x = (int)((u32)f32_to_bf16(a.x) | ((u32)f32_to_bf16(a.y) << 16));
  o.y = (int)((u32)f32_to_bf16(a.z) | ((u32)f32_to_bf16(a.w) << 16));
  o.z = (int)((u32)f32_to_bf16(b.x) | ((u32)f32_to_bf16(b.y) << 16));
  o.w = (int)((u32)f32_to_bf16(b.z) | ((u32)f32_to_bf16(b.w) << 16));
  ((int4*)Xb)[i] = o;
}

// ---------------------------------------------------------------------------
// K1 round-7: L2-LOCAL counter atomics.
// Evidence history: r4->r5 permuted layout (WRITE 55->48MB), r5->r6
// persistent-resident blocks (no change). Conclusion: WRITE ~= 1.2M x ~40B
// = the ATOMICS themselves. Device-scope atomicAdd must execute at the
// cross-XCD coherent point (L3/fabric), bypassing L2 no matter where the
// block runs -- routing could never fix it. 1.2M fabric RMWs / 57us = the
// whole kernel time (VALU 5%, BW 15%: everything else idle).
// Fix: workgroup-scope atomics (execute IN the local L2, cached, fast),
// made correct by PHYSICAL routing: each block reads its real XCC_ID
// (s_getreg, measured m09) and claims slices from queue[xcc_id], processing
// only edges with dst&7 == xcc_id. All atomics on a given counter thus come
// from ONE XCD's L2 by construction -- not by dispatch assumption. A
// separate sweeper kernel (launch boundary = global barrier + L2 flush)
// handles any queue a block-less XCD left behind with device-scope atomics
// (normally zero work), so correctness never depends on dispatch mapping.
// cnt filter regions are 64B-aligned (nxc padded) so fast/sweep scopes never
// share a cache line.
// ---------------------------------------------------------------------------
template <bool WG>
__device__ __forceinline__ void process_slice(
    const int* __restrict__ ra, const int* __restrict__ rb,
    int* __restrict__ cnt_f, int* __restrict__ adj_f, int nedges, int slice,
    int myx) {
  int t = slice * 256 + threadIdx.x;  // int2 index
  int e0 = t * 2;
  if (e0 >= nedges) return;
  bool has1 = (e0 + 1) < nedges;
  long long apk = __builtin_nontemporal_load((const long long*)ra + t);
  long long bpk = __builtin_nontemporal_load((const long long*)rb + t);
  int2 av = make_int2((int)apk, (int)(apk >> 32));
  int2 bv = make_int2((int)bpk, (int)(bpk >> 32));

  int d[4], s[4];
  d[0] = av.x; s[0] = bv.x;
  d[1] = bv.x; s[1] = av.x;
  d[2] = has1 ? av.y : -1; s[2] = bv.y;
  d[3] = has1 ? bv.y : -1; s[3] = av.y;
#pragma unroll
  for (int i = 0; i < 4; ++i) {
    if (d[i] >= 0 && (d[i] & 7) == myx) {
      int b = d[i] >> 3;
      int p;
      if (WG)
        p = __hip_atomic_fetch_add(&cnt_f[b], 1, __ATOMIC_RELAXED,
                                   __HIP_MEMORY_SCOPE_WORKGROUP);
      else
        p = atomicAdd(&cnt_f[b], 1);
      if (p < CAP) adj_f[(size_t)b * CAP + p] = s[i];
    }
  }
}

__global__ __launch_bounds__(256) void fill_adj_fast_kernel(
    const int* __restrict__ ra, const int* __restrict__ rb,
    int* __restrict__ q, int* __restrict__ cnt, int* __restrict__ adj,
    int nedges, int nx, int nxc, int nslices) {
  __shared__ int s_slice;
  int x;
  asm volatile("s_getreg_b32 %0, hwreg(HW_REG_XCC_ID)" : "=s"(x));
  x &= 7;  // physical XCD of this block
  int* cnt_f = cnt + (size_t)x * nxc;
  int* adj_f = adj + (size_t)x * nx * CAP;
  for (;;) {
    if (threadIdx.x == 0) s_slice = atomicAdd(&q[x], 1);  // device scope, rare
    __syncthreads();
    int slice = s_slice;
    __syncthreads();
    if (slice >= nslices) break;
    process_slice<true>(ra, rb, cnt_f, adj_f, nedges, slice, x);
  }
}

// Sweeper: separate launch (implicit global barrier + L2 writeback between
// kernels). For each filter f, slices [q[f], nslices) were never claimed
// (only possible if XCD f had no resident blocks -- normally empty range);
// process them with device-scope atomics.
__global__ __launch_bounds__(256) void fill_adj_sweep_kernel(
    const int* __restrict__ ra, const int* __restrict__ rb,
    const int* __restrict__ q, int* __restrict__ cnt, int* __restrict__ adj,
    int nedges, int nx, int nxc, int nslices) {
  int f = blockIdx.x;  // 0..7
  int* cnt_f = cnt + (size_t)f * nxc;
  int* adj_f = adj + (size_t)f * nx * CAP;
  int start = q[f];
  if (start > nslices) start = nslices;
  for (int s = start; s < nslices; ++s)
    process_slice<false>(ra, rb, cnt_f, adj_f, nedges, s, f);
}

// ---------------------------------------------------------------------------
// K2: gather-aggregate over bf16 X. TWO nodes per wave: half-wave (32 lanes)
// per node, uint2 (4 bf16 feats) per lane. Buckets addressed through the
// permuted index; second 128B of the bucket only read when degree > 32.
// fp32 accumulate; result written as a bf16 row into the node's own bucket
// (fully consumed before the store; buckets disjoint -> race-free).
// ---------------------------------------------------------------------------
__global__ void gather_agg_kernel(const u16* __restrict__ Xb,
                                  const int* __restrict__ cnt,
                                  int* __restrict__ adj,
                                  int nnodes, int nx, int nxc) {
  int gid = blockIdx.x * blockDim.x + threadIdx.x;
  int wid = gid >> 6;
  int l = gid & 63;
  int half = l >> 5;
  int hl = l & 31;
  int node = wid * 2 + half;
  if (node >= nnodes) return;
  const uint2* Xv = (const uint2*)Xb;  // row = 32 uint2 (256 B)
  const int f = node & 7, v = node >> 3;
  const int bkt = f * nx + v;
  const int* lst = adj + (size_t)bkt * CAP;
  int n = cnt[(size_t)f * nxc + v];
  if (n > CAP) n = CAP;
  int idx0 = lst[hl];                           // positions 0..31
  int idx1 = (n > 32) ? lst[hl + 32] : 0;       // positions 32..63 (rare)
  uint2 ps = Xv[(size_t)node * 32 + hl];
  float a0 = __uint_as_float(ps.x << 16);
  float a1 = __uint_as_float(ps.x & 0xffff0000u);
  float a2 = __uint_as_float(ps.y << 16);
  float a3 = __uint_as_float(ps.y & 0xffff0000u);
  const int base = half << 5;
  for (int k = 0; k < n; k += 8) {
    uint2 pv[8];
#pragma unroll
    for (int t = 0; t < 8; ++t) {
      int pos = k + t;
      int sel = (pos < 32) ? idx0 : idx1;
      int nb = __shfl(sel, base + (pos & 31));
      pv[t] = (pos < n) ? Xv[(size_t)nb * 32 + hl] : make_uint2(0u, 0u);
    }
#pragma unroll
    for (int t = 0; t < 8; ++t) {
      a0 += __uint_as_float(pv[t].x << 16);
      a1 += __uint_as_float(pv[t].x & 0xffff0000u);
      a2 += __uint_as_float(pv[t].y << 16);
      a3 += __uint_as_float(pv[t].y & 0xffff0000u);
    }
  }
  u32 w0 = (u32)f32_to_bf16(a0) | ((u32)f32_to_bf16(a1) << 16);
  u32 w1 = (u32)f32_to_bf16(a2) | ((u32)f32_to_bf16(a3) << 16);
  ((uint2*)adj)[(size_t)bkt * 32 + hl] = make_uint2(w0, w1);
}

// ---------------------------------------------------------------------------
// K3: transpose+convert weights fp32 -> bf16 (W^T layout [n][k]) into the
// dead `q/cnt` region (runs after gather).
// ---------------------------------------------------------------------------
__global__ void convert_w_kernel(const float* __restrict__ Wh,
                                 const float* __restrict__ Wo,
                                 u16* __restrict__ WhT,
                                 u16* __restrict__ WoT) {
  int idx = blockIdx.x * 256 + threadIdx.x;  // 0..32767
  const float* src = (idx < 16384) ? Wh : Wo;
  u16* dst = (idx < 16384) ? WhT : WoT;
  int i = idx & 16383;
  int k = i >> 7, n = i & 127;
  dst[n * 128 + k] = f32_to_bf16(src[k * 128 + n]);
}

// ---------------------------------------------------------------------------
// K4: fused MLP via bf16 MFMA (16x16x32). Xagg rows addressed through the
// permuted bucket index (each row is still a contiguous 256B chunk;
// 16-thread row loads stay fully coalesced).
// ---------------------------------------------------------------------------
__global__ __launch_bounds__(256) void mlp_mfma_kernel(
    const u16* __restrict__ Xagg,  // bucket-permuted [b(v)][128] bf16
    const u16* __restrict__ WhT,   // [128][128] bf16, [n][k]
    const u16* __restrict__ WoT,   // [128][128] bf16, [n][k]
    const float* __restrict__ bh,
    const float* __restrict__ bo,
    float* __restrict__ out, int nnodes, int nx) {
  __shared__ u16 smem[2 * 128 * 128];  // 64 KB
  u16* sA = smem;
  u16* sW = smem + 16384;

  const int tid = threadIdx.x;
  const int w = tid >> 6;
  const int l = tid & 63;
  const int l15 = l & 15;
  const int l4 = l >> 4;  // quad 0..3
  const int r0 = blockIdx.x * 128;

  // ---- stage sA (Xagg tile, permuted rows) and sW (Wh^T), swizzled 16B ----
#pragma unroll
  for (int t = 0; t < 8; ++t) {
    int id = tid + t * 256;  // 0..2047 : 128 rows x 16 units
    int r = id >> 4, u = id & 15;
    int gr = r0 + r;
    if (gr >= nnodes) gr = nnodes - 1;
    size_t xrow = (size_t)((gr & 7) * nx + (gr >> 3)) * 128;
    *(int4*)&sA[r * 128 + ((u ^ (r & 15)) * 8)] =
        *(const int4*)&Xagg[xrow + u * 8];
    *(int4*)&sW[r * 128 + ((u ^ (r & 15)) * 8)] =
        *(const int4*)&WhT[r * 128 + u * 8];
  }

  float bhv[8], bov[8];
#pragma unroll
  for (int j = 0; j < 8; ++j) {
    bhv[j] = bh[j * 16 + l15];
    bov[j] = bo[j * 16 + l15];
  }
  __syncthreads();

  const int m0 = w * 32 + l15;       // A row, m-tile 0
  const int m1 = w * 32 + 16 + l15;  // A row, m-tile 1

  f32x4 acc[2][8];
#pragma unroll
  for (int i = 0; i < 2; ++i)
#pragma unroll
    for (int j = 0; j < 8; ++j) acc[i][j] = (f32x4){0.f, 0.f, 0.f, 0.f};

  // ---- GEMM1: hidden = Xagg @ Wh ----
#pragma unroll
  for (int c = 0; c < 4; ++c) {  // K chunks of 32
    int pu = ((c * 4 + l4) ^ l15) * 8;
    bf16x8 a0 = *(bf16x8*)&sA[m0 * 128 + pu];
    bf16x8 a1 = *(bf16x8*)&sA[m1 * 128 + pu];
#pragma unroll
    for (int j = 0; j < 8; ++j) {
      bf16x8 bfr = *(bf16x8*)&sW[(j * 16 + l15) * 128 + pu];
      acc[0][j] = __builtin_amdgcn_mfma_f32_16x16x32_bf16(a0, bfr, acc[0][j], 0, 0, 0);
      acc[1][j] = __builtin_amdgcn_mfma_f32_16x16x32_bf16(a1, bfr, acc[1][j], 0, 0, 0);
    }
  }

  __syncthreads();  // all waves done reading sW (GEMM1)

  // ---- restage sW with Wo^T ----
#pragma unroll
  for (int t = 0; t < 8; ++t) {
    int id = tid + t * 256;
    int r = id >> 4, u = id & 15;
    *(int4*)&sW[r * 128 + ((u ^ (r & 15)) * 8)] =
        *(const int4*)&WoT[r * 128 + u * 8];
  }

  // ---- bias + relu + bf16, write hidden into sA (own rows only) ----
#pragma unroll
  for (int i = 0; i < 2; ++i)
#pragma unroll
    for (int j = 0; j < 8; ++j)
#pragma unroll
      for (int r = 0; r < 4; ++r) {
        int m = w * 32 + i * 16 + l4 * 4 + r;
        float v = fmaxf(acc[i][j][r] + bhv[j], 0.f);
        int k = j * 16 + l15;
        sA[m * 128 + (((k >> 3) ^ (m & 15)) * 8) + (k & 7)] = f32_to_bf16(v);
      }
  __syncthreads();

  // ---- GEMM2: out = hidden @ Wo (reuse acc) ----
#pragma unroll
  for (int i = 0; i < 2; ++i)
#pragma unroll
    for (int j = 0; j < 8; ++j) acc[i][j] = (f32x4){0.f, 0.f, 0.f, 0.f};

#pragma unroll
  for (int c = 0; c < 4; ++c) {
    int pu = ((c * 4 + l4) ^ l15) * 8;
    bf16x8 a0 = *(bf16x8*)&sA[m0 * 128 + pu];
    bf16x8 a1 = *(bf16x8*)&sA[m1 * 128 + pu];
#pragma unroll
    for (int j = 0; j < 8; ++j) {
      bf16x8 bfr = *(bf16x8*)&sW[(j * 16 + l15) * 128 + pu];
      acc[0][j] = __builtin_amdgcn_mfma_f32_16x16x32_bf16(a0, bfr, acc[0][j], 0, 0, 0);
      acc[1][j] = __builtin_amdgcn_mfma_f32_16x16x32_bf16(a1, bfr, acc[1][j], 0, 0, 0);
    }
  }

  __syncthreads();  // everyone done with sA/sW -> reuse as fp32 out stage

  // ---- epilogue: + bo, stage in LDS, coalesced dwordx4 stores ----
  float* sOut = (float*)smem;  // 128 x 128 fp32 = 64 KB
#pragma unroll
  for (int i = 0; i < 2; ++i)
#pragma unroll
    for (int j = 0; j < 8; ++j)
#pragma unroll
      for (int r = 0; r < 4; ++r) {
        int m = w * 32 + i * 16 + l4 * 4 + r;
        sOut[m * 128 + j * 16 + l15] = acc[i][j][r] + bov[j];
      }
  __syncthreads();
#pragma unroll
  for (int t = 0; t < 16; ++t) {
    int id = tid + t * 256;  // 0..4095 float4 units
    int r = id >> 5, u4 = id & 31;
    int gr = r0 + r;
    if (gr < nnodes)
      ((float4*)out)[(size_t)gr * 32 + u4] = ((const float4*)sOut)[id];
  }
}

// ---------------------------------------------------------------------------
extern "C" void kernel_launch(void* const* d_in, const int* in_sizes, int n_in,
                              void* d_out, int out_size, void* d_ws,
                              size_t ws_size, hipStream_t stream) {
  const float* X = (const float*)d_in[0];
  const int* ra = (const int*)d_in[1];
  const int* rb = (const int*)d_in[2];
  const float* Wh = (const float*)d_in[3];
  const float* bh = (const float*)d_in[4];
  const float* Wo = (const float*)d_in[5];
  const float* bo = (const float*)d_in[6];
  float* out = (float*)d_out;

  int nnodes = in_sizes[0] / 128;
  int nedges = in_sizes[1];
  int nx = (nnodes + 7) / 8;     // nodes per XCD region (adj stride)
  int nxc = (nx + 15) & ~15;     // cnt stride: 64B-aligned filter regions

  // ws layout: [q: 16 ints | cnt: 8*nxc ints | adj: 8*nx*CAP ints] (~26 MB).
  // Xb (bf16 X) lives in d_out until mlp overwrites it (gather consumed it).
  // After gather: adj holds Xagg bf16 rows; q/cnt region dead -> WhT/WoT.
  int* q = (int*)d_ws;
  int* cnt = q + 16;
  int* adj = cnt + (size_t)8 * nxc;
  u16* WhT = (u16*)d_ws;
  u16* WoT = WhT + 16384;
  u16* Xb = (u16*)d_out;

  int n8 = nnodes * 16;  // 128 feats / 8 per thread
  hipMemsetAsync(d_ws, 0, (size_t)(16 + 8 * nxc) * 4, stream);
  convert_x_kernel<<<(n8 + 255) / 256, 256, 0, stream>>>(X, Xb, n8);
  int nslices = ((nedges + 1) / 2 + 255) / 256;  // 512 edges per slice
  // 2048 blocks (max occupancy); any dispatch placement is correct since
  // each block derives its filter from its physical XCC_ID.
  fill_adj_fast_kernel<<<2048, 256, 0, stream>>>(ra, rb, q, cnt, adj, nedges,
                                                 nx, nxc, nslices);
  fill_adj_sweep_kernel<<<8, 256, 0, stream>>>(ra, rb, q, cnt, adj, nedges,
                                               nx, nxc, nslices);
  int nwaves = (nnodes + 1) / 2;
  gather_agg_kernel<<<(nwaves * 64 + 255) / 256, 256, 0, stream>>>(
      Xb, cnt, adj, nnodes, nx, nxc);
  convert_w_kernel<<<128, 256, 0, stream>>>(Wh, Wo, WhT, WoT);
  mlp_mfma_kernel<<<(nnodes + 127) / 128, 256, 0, stream>>>(
      (const u16*)adj, WhT, WoT, bh, bo, out, nnodes, nx);
}

// Round 4
// 211.584 us; speedup vs baseline: 1.5533x; 1.5533x over previous
//
#include <hip/hip_runtime.h>

#define CAP 64
#define BCAP 4096         // entries per bin region (mean ~3070, ~18 sigma headroom)
#define RADIX_UNITS 4096  // int2 units per radix block = 8192 edges = 16/thread

typedef short bf16x8 __attribute__((ext_vector_type(8)));
typedef float f32x4 __attribute__((ext_vector_type(4)));
typedef unsigned short u16;
typedef unsigned int u32;

__device__ __forceinline__ u16 f32_to_bf16(float f) {
  u32 b = __float_as_uint(f);
  b += 0x7fffu + ((b >> 16) & 1u);  // round to nearest even
  return (u16)(b >> 16);
}

// ---------------------------------------------------------------------------
// K1 round-8: ATOMIC-FREE adjacency build (two-pass radix), fused with
// convert_x. Evidence r4-r7: 1.2M device-scope returning atomics are
// irreducible via routing/scope (WRITE stuck at 48MB, 56us = 21G atomics/s
// fabric ceiling). So eliminate them:
//  scan1: per-block LDS histogram over coarse bins (dst>>8, 256 nodes/bin),
//         then ONE global atomicAdd per (block,bin) (~29k total) to reserve
//         contiguous bin space.
//  scan2: re-read (L2-hot) edges, scatter (dst,src) pairs into bin regions;
//         a block's slots per bin are contiguous -> near-full-line writes.
// Blocks beyond nradix do the X fp32->bf16 convert (fill path never
// saturated BW, so the copy hides under it).
// Bin regions live in the dead 2nd half of d_out (freed before mlp writes).
// ---------------------------------------------------------------------------
__global__ __launch_bounds__(256) void front_kernel(
    const float* __restrict__ X, u16* __restrict__ Xb, int n8,
    const int* __restrict__ ra, const int* __restrict__ rb,
    int* __restrict__ gOff, int2* __restrict__ binned, int nedges, int nunits,
    int nbins, int nradix) {
  if ((int)blockIdx.x >= nradix) {
    // ---- convert_x path ----
    int i = ((int)blockIdx.x - nradix) * 256 + threadIdx.x;
    if (i >= n8) return;
    float4 a = ((const float4*)X)[2 * i];
    float4 b = ((const float4*)X)[2 * i + 1];
    int4 o;
    o.x = (int)((u32)f32_to_bf16(a.x) | ((u32)f32_to_bf16(a.y) << 16));
    o.y = (int)((u32)f32_to_bf16(a.z) | ((u32)f32_to_bf16(a.w) << 16));
    o.z = (int)((u32)f32_to_bf16(b.x) | ((u32)f32_to_bf16(b.y) << 16));
    o.w = (int)((u32)f32_to_bf16(b.z) | ((u32)f32_to_bf16(b.w) << 16));
    ((int4*)Xb)[i] = o;
    return;
  }
  // ---- radix scatter path ----
  __shared__ int lh[512];  // bin histogram, then running slot position
  const int tid = threadIdx.x;
  for (int b = tid; b < nbins; b += 256) lh[b] = 0;
  __syncthreads();
  const int u0 = (int)blockIdx.x * RADIX_UNITS;

  // scan 1: count entries per bin
  for (int k = 0; k < RADIX_UNITS / 256; ++k) {
    int u = u0 + k * 256 + tid;
    if (u < nunits) {
      long long apk = ((const long long*)ra)[u];
      long long bpk = ((const long long*)rb)[u];
      int a0 = (int)apk, a1 = (int)(apk >> 32);
      int b0 = (int)bpk, b1 = (int)(bpk >> 32);
      bool has1 = (2 * u + 1) < nedges;
      atomicAdd(&lh[a0 >> 8], 1);
      atomicAdd(&lh[b0 >> 8], 1);
      if (has1) {
        atomicAdd(&lh[a1 >> 8], 1);
        atomicAdd(&lh[b1 >> 8], 1);
      }
    }
  }
  __syncthreads();
  // reserve contiguous space per bin (one device atomic per block,bin)
  for (int b = tid; b < nbins; b += 256) {
    int c = lh[b];
    lh[b] = (c > 0) ? atomicAdd(&gOff[b], c) : 0;
  }
  __syncthreads();
  // scan 2: place (dst,src) pairs at block-contiguous slots
  for (int k = 0; k < RADIX_UNITS / 256; ++k) {
    int u = u0 + k * 256 + tid;
    if (u < nunits) {
      long long apk = ((const long long*)ra)[u];
      long long bpk = ((const long long*)rb)[u];
      int a0 = (int)apk, a1 = (int)(apk >> 32);
      int b0 = (int)bpk, b1 = (int)(bpk >> 32);
      bool has1 = (2 * u + 1) < nedges;
      int d[4], s[4];
      d[0] = a0; s[0] = b0;
      d[1] = b0; s[1] = a0;
      d[2] = has1 ? a1 : -1; s[2] = b1;
      d[3] = has1 ? b1 : -1; s[3] = a1;
#pragma unroll
      for (int i = 0; i < 4; ++i) {
        if (d[i] >= 0) {
          int b = d[i] >> 8;
          int slot = atomicAdd(&lh[b], 1);
          if (slot < BCAP) binned[(size_t)b * BCAP + slot] = make_int2(d[i], s[i]);
        }
      }
    }
  }
}

// ---------------------------------------------------------------------------
// K1b: per-bin adjacency build. One block per 256-node bin: stream the bin's
// pairs (coalesced), slot via LDS atomics, plain stores into the bin's
// contiguous 64KB adj region (L2-resident, one writeback). Writes cnt for
// every node (memset-free).
// ---------------------------------------------------------------------------
__global__ __launch_bounds__(256) void bin_build_kernel(
    const int2* __restrict__ binned, const int* __restrict__ gOff,
    int* __restrict__ cnt, int* __restrict__ adj, int nnodes) {
  __shared__ int lc[256];
  const int bin = blockIdx.x;
  lc[threadIdx.x] = 0;
  __syncthreads();
  int count = gOff[bin];
  if (count > BCAP) count = BCAP;
  const int2* src = binned + (size_t)bin * BCAP;
  for (int i = threadIdx.x; i < count; i += 256) {
    int2 e = src[i];
    int p = atomicAdd(&lc[e.x & 255], 1);
    if (p < CAP) adj[(size_t)e.x * CAP + p] = e.y;
  }
  __syncthreads();
  int node = bin * 256 + threadIdx.x;
  if (node < nnodes) cnt[node] = lc[threadIdx.x];
}

// ---------------------------------------------------------------------------
// K2: gather-aggregate over bf16 X (r0-proven plain indexing + r1's
// degree<=32 read skip). TWO nodes per wave, half-wave per node, uint2 per
// lane. fp32 accumulate; result written as bf16 row into the node's own adj
// bucket (fully consumed before the store; buckets disjoint -> race-free).
// ---------------------------------------------------------------------------
__global__ void gather_agg_kernel(const u16* __restrict__ Xb,
                                  const int* __restrict__ cnt,
                                  int* __restrict__ adj, int nnodes) {
  int gid = blockIdx.x * blockDim.x + threadIdx.x;
  int wid = gid >> 6;
  int l = gid & 63;
  int half = l >> 5;
  int hl = l & 31;
  int node = wid * 2 + half;
  if (node >= nnodes) return;
  const uint2* Xv = (const uint2*)Xb;  // row = 32 uint2 (256 B)
  const int* lst = adj + (size_t)node * CAP;
  int n = cnt[node];
  if (n > CAP) n = CAP;
  int idx0 = lst[hl];                      // positions 0..31
  int idx1 = (n > 32) ? lst[hl + 32] : 0;  // positions 32..63 (rare)
  uint2 ps = Xv[(size_t)node * 32 + hl];
  float a0 = __uint_as_float(ps.x << 16);
  float a1 = __uint_as_float(ps.x & 0xffff0000u);
  float a2 = __uint_as_float(ps.y << 16);
  float a3 = __uint_as_float(ps.y & 0xffff0000u);
  const int base = half << 5;
  for (int k = 0; k < n; k += 8) {
    uint2 pv[8];
#pragma unroll
    for (int t = 0; t < 8; ++t) {
      int pos = k + t;
      int sel = (pos < 32) ? idx0 : idx1;
      int nb = __shfl(sel, base + (pos & 31));
      pv[t] = (pos < n) ? Xv[(size_t)nb * 32 + hl] : make_uint2(0u, 0u);
    }
#pragma unroll
    for (int t = 0; t < 8; ++t) {
      a0 += __uint_as_float(pv[t].x << 16);
      a1 += __uint_as_float(pv[t].x & 0xffff0000u);
      a2 += __uint_as_float(pv[t].y << 16);
      a3 += __uint_as_float(pv[t].y & 0xffff0000u);
    }
  }
  u32 w0 = (u32)f32_to_bf16(a0) | ((u32)f32_to_bf16(a1) << 16);
  u32 w1 = (u32)f32_to_bf16(a2) | ((u32)f32_to_bf16(a3) << 16);
  ((uint2*)adj)[(size_t)node * 32 + hl] = make_uint2(w0, w1);
}

// ---------------------------------------------------------------------------
// K3: transpose+convert weights fp32 -> bf16 (W^T layout [n][k]) into the
// dead `cnt` region (runs after gather).
// ---------------------------------------------------------------------------
__global__ void convert_w_kernel(const float* __restrict__ Wh,
                                 const float* __restrict__ Wo,
                                 u16* __restrict__ WhT,
                                 u16* __restrict__ WoT) {
  int idx = blockIdx.x * 256 + threadIdx.x;  // 0..32767
  const float* src = (idx < 16384) ? Wh : Wo;
  u16* dst = (idx < 16384) ? WhT : WoT;
  int i = idx & 16383;
  int k = i >> 7, n = i & 127;
  dst[n * 128 + k] = f32_to_bf16(src[k * 128 + n]);
}

// ---------------------------------------------------------------------------
// K4: fused MLP via bf16 MFMA (16x16x32) -- r0-proven version.
// ---------------------------------------------------------------------------
__global__ __launch_bounds__(256) void mlp_mfma_kernel(
    const u16* __restrict__ Xagg,  // [nnodes][128] bf16 (lives in adj region)
    const u16* __restrict__ WhT,   // [128][128] bf16, [n][k]
    const u16* __restrict__ WoT,   // [128][128] bf16, [n][k]
    const float* __restrict__ bh,
    const float* __restrict__ bo,
    float* __restrict__ out, int nnodes) {
  __shared__ u16 smem[2 * 128 * 128];  // 64 KB
  u16* sA = smem;
  u16* sW = smem + 16384;

  const int tid = threadIdx.x;
  const int w = tid >> 6;
  const int l = tid & 63;
  const int l15 = l & 15;
  const int l4 = l >> 4;  // quad 0..3
  const int r0 = blockIdx.x * 128;

  // ---- stage sA (Xagg tile) and sW (Wh^T), swizzled 16B units ----
#pragma unroll
  for (int t = 0; t < 8; ++t) {
    int id = tid + t * 256;  // 0..2047 : 128 rows x 16 units
    int r = id >> 4, u = id & 15;
    int gr = r0 + r;
    if (gr >= nnodes) gr = nnodes - 1;
    *(int4*)&sA[r * 128 + ((u ^ (r & 15)) * 8)] =
        *(const int4*)&Xagg[(size_t)gr * 128 + u * 8];
    *(int4*)&sW[r * 128 + ((u ^ (r & 15)) * 8)] =
        *(const int4*)&WhT[r * 128 + u * 8];
  }

  float bhv[8], bov[8];
#pragma unroll
  for (int j = 0; j < 8; ++j) {
    bhv[j] = bh[j * 16 + l15];
    bov[j] = bo[j * 16 + l15];
  }
  __syncthreads();

  const int m0 = w * 32 + l15;       // A row, m-tile 0
  const int m1 = w * 32 + 16 + l15;  // A row, m-tile 1

  f32x4 acc[2][8];
#pragma unroll
  for (int i = 0; i < 2; ++i)
#pragma unroll
    for (int j = 0; j < 8; ++j) acc[i][j] = (f32x4){0.f, 0.f, 0.f, 0.f};

  // ---- GEMM1: hidden = Xagg @ Wh ----
#pragma unroll
  for (int c = 0; c < 4; ++c) {  // K chunks of 32
    int pu = ((c * 4 + l4) ^ l15) * 8;
    bf16x8 a0 = *(bf16x8*)&sA[m0 * 128 + pu];
    bf16x8 a1 = *(bf16x8*)&sA[m1 * 128 + pu];
#pragma unroll
    for (int j = 0; j < 8; ++j) {
      bf16x8 bfr = *(bf16x8*)&sW[(j * 16 + l15) * 128 + pu];
      acc[0][j] = __builtin_amdgcn_mfma_f32_16x16x32_bf16(a0, bfr, acc[0][j], 0, 0, 0);
      acc[1][j] = __builtin_amdgcn_mfma_f32_16x16x32_bf16(a1, bfr, acc[1][j], 0, 0, 0);
    }
  }

  __syncthreads();  // all waves done reading sW (GEMM1)

  // ---- restage sW with Wo^T ----
#pragma unroll
  for (int t = 0; t < 8; ++t) {
    int id = tid + t * 256;
    int r = id >> 4, u = id & 15;
    *(int4*)&sW[r * 128 + ((u ^ (r & 15)) * 8)] =
        *(const int4*)&WoT[r * 128 + u * 8];
  }

  // ---- bias + relu + bf16, write hidden into sA (own rows only) ----
#pragma unroll
  for (int i = 0; i < 2; ++i)
#pragma unroll
    for (int j = 0; j < 8; ++j)
#pragma unroll
      for (int r = 0; r < 4; ++r) {
        int m = w * 32 + i * 16 + l4 * 4 + r;
        float v = fmaxf(acc[i][j][r] + bhv[j], 0.f);
        int k = j * 16 + l15;
        sA[m * 128 + (((k >> 3) ^ (m & 15)) * 8) + (k & 7)] = f32_to_bf16(v);
      }
  __syncthreads();

  // ---- GEMM2: out = hidden @ Wo (reuse acc) ----
#pragma unroll
  for (int i = 0; i < 2; ++i)
#pragma unroll
    for (int j = 0; j < 8; ++j) acc[i][j] = (f32x4){0.f, 0.f, 0.f, 0.f};

#pragma unroll
  for (int c = 0; c < 4; ++c) {
    int pu = ((c * 4 + l4) ^ l15) * 8;
    bf16x8 a0 = *(bf16x8*)&sA[m0 * 128 + pu];
    bf16x8 a1 = *(bf16x8*)&sA[m1 * 128 + pu];
#pragma unroll
    for (int j = 0; j < 8; ++j) {
      bf16x8 bfr = *(bf16x8*)&sW[(j * 16 + l15) * 128 + pu];
      acc[0][j] = __builtin_amdgcn_mfma_f32_16x16x32_bf16(a0, bfr, acc[0][j], 0, 0, 0);
      acc[1][j] = __builtin_amdgcn_mfma_f32_16x16x32_bf16(a1, bfr, acc[1][j], 0, 0, 0);
    }
  }

  __syncthreads();  // everyone done with sA/sW -> reuse as fp32 out stage

  // ---- epilogue: + bo, stage in LDS, coalesced dwordx4 stores ----
  float* sOut = (float*)smem;  // 128 x 128 fp32 = 64 KB
#pragma unroll
  for (int i = 0; i < 2; ++i)
#pragma unroll
    for (int j = 0; j < 8; ++j)
#pragma unroll
      for (int r = 0; r < 4; ++r) {
        int m = w * 32 + i * 16 + l4 * 4 + r;
        sOut[m * 128 + j * 16 + l15] = acc[i][j][r] + bov[j];
      }
  __syncthreads();
#pragma unroll
  for (int t = 0; t < 16; ++t) {
    int id = tid + t * 256;  // 0..4095 float4 units
    int r = id >> 5, u4 = id & 31;
    int gr = r0 + r;
    if (gr < nnodes)
      ((float4*)out)[(size_t)gr * 32 + u4] = ((const float4*)sOut)[id];
  }
}

// ---------------------------------------------------------------------------
extern "C" void kernel_launch(void* const* d_in, const int* in_sizes, int n_in,
                              void* d_out, int out_size, void* d_ws,
                              size_t ws_size, hipStream_t stream) {
  const float* X = (const float*)d_in[0];
  const int* ra = (const int*)d_in[1];
  const int* rb = (const int*)d_in[2];
  const float* Wh = (const float*)d_in[3];
  const float* bh = (const float*)d_in[4];
  const float* Wo = (const float*)d_in[5];
  const float* bo = (const float*)d_in[6];
  float* out = (float*)d_out;

  int nnodes = in_sizes[0] / 128;
  int nedges = in_sizes[1];
  int nunits = (nedges + 1) / 2;         // int2 edge units
  int nbins = (nnodes + 255) >> 8;       // 256-node coarse bins
  int nradix = (nunits + RADIX_UNITS - 1) / RADIX_UNITS;

  // ws layout (proven 26.0 MB): [cnt: nnodes ints | adj: nnodes*CAP ints].
  // After gather: adj holds Xagg bf16 rows; cnt dead -> WhT/WoT overlay.
  int* cnt = (int*)d_ws;
  int* adj = cnt + nnodes;
  u16* WhT = (u16*)d_ws;
  u16* WoT = WhT + 16384;
  // d_out transient layout: [Xb: nnodes*256B | binned: nbins*BCAP*8B | gOff]
  // (binned/gOff dead before mlp writes out; Xb consumed by gather).
  u16* Xb = (u16*)d_out;
  int2* binned = (int2*)((char*)d_out + (size_t)nnodes * 256);
  int* gOff = (int*)((char*)binned + (size_t)nbins * BCAP * sizeof(int2));

  int n8 = nnodes * 16;  // 128 feats / 8 per thread
  int nconv = (n8 + 255) / 256;
  hipMemsetAsync(gOff, 0, (size_t)nbins * 4, stream);
  front_kernel<<<nradix + nconv, 256, 0, stream>>>(
      X, Xb, n8, ra, rb, gOff, binned, nedges, nunits, nbins, nradix);
  bin_build_kernel<<<nbins, 256, 0, stream>>>(binned, gOff, cnt, adj, nnodes);
  int nwaves = (nnodes + 1) / 2;
  gather_agg_kernel<<<(nwaves * 64 + 255) / 256, 256, 0, stream>>>(Xb, cnt,
                                                                   adj, nnodes);
  convert_w_kernel<<<128, 256, 0, stream>>>(Wh, Wo, WhT, WoT);
  mlp_mfma_kernel<<<(nnodes + 127) / 128, 256, 0, stream>>>(
      (const u16*)adj, WhT, WoT, bh, bo, out, nnodes);
}